// Round 8
// baseline (515.886 us; speedup 1.0000x reference)
//
#include <hip/hip_runtime.h>

#define NFEAT 128
#define HID 16
#define NOUT 2
#define NGRAPH 64

#define BN 196                     // nodes per bucket
#define NBUCK 512                  // 512 buckets -> 2 blocks/CU on 256 CUs
#define NCB 512                    // count/scatter chunks (1024-thr blocks, 2/CU)
#define CH 12500                   // chunk length = E/NCB exactly
#define EPT 13                     // edges per thread (13*1024 >= 12500)
#define GCNT_TOT (NBUCK * NCB)     // 262144
#define SCAN_NB 256                // scan blocks: 256*1024 == GCNT_TOT
#define PSTRIDE 192                // 128 graph sums + 64 counts
#define WST 132                    // sWT row stride (floats): 128+4 pad
#define ACST 9                     // bg1 u64 acc stride (odd -> bank-pair spread)

// fixed-point scales (int LDS atomics: ds_add_u32/u64 fast; ds_add_f32 ~200cy)
#define S20F 1048576.0f            // 2^20 (bg1 features)
#define S20I 9.5367431640625e-7f   // 2^-20
#define S18F 262144.0f             // 2^18 (bg2 components)
#define S18I 3.814697265625e-6f    // 2^-18
#define SPF  32768.0f              // 2^15 (graph bins)
#define SPI  3.0517578125e-5f      // 2^-15
#define OFF23 0x800000             // per-addend bias, bg1 fields
#define OFF22 0x400000             // per-addend bias, bg2 fields

typedef unsigned short ushortv8 __attribute__((ext_vector_type(8)));
typedef float fvec4 __attribute__((ext_vector_type(4)));

// XCD-aware chunk remap: consecutive chunks stay on one XCD (8 XCDs, rr dispatch)
__device__ __forceinline__ int chunk_id(int bid) { return ((bid & 7) << 6) | (bid >> 3); }

// RNE float -> bf16 bits
__device__ __forceinline__ unsigned short f2bf(float f) {
    unsigned u = __float_as_uint(f);
    return (unsigned short)((u + 0x7FFFu + ((u >> 16) & 1u)) >> 16);
}

__device__ __forceinline__ float bf2f(unsigned short b) {
    return __uint_as_float(((unsigned)b) << 16);
}

__device__ __forceinline__ unsigned bucket_of(int d) { return (unsigned)d / (unsigned)BN; }

// ---------------- count: per-(bucket, chunk) histogram + global degree -----
__global__ __launch_bounds__(1024) void k_count(const int* __restrict__ dst, int* __restrict__ gcnt,
                                                int* __restrict__ degg, int E) {
    __shared__ int c[NBUCK];
    int t = threadIdx.x;
    int cid = chunk_id(blockIdx.x);
    for (int i = t; i < NBUCK; i += 1024) c[i] = 0;
    __syncthreads();
    int start = cid * CH;
    int end = min(E, start + CH);
    for (int e = start + t; e < end; e += 1024) {
        int d = __builtin_nontemporal_load(dst + e);
        atomicAdd(&c[bucket_of(d)], 1);
        atomicAdd(&degg[d], 1);          // fire-and-forget: no return, no wait
    }
    __syncthreads();
    for (int i = t; i < NBUCK; i += 1024) gcnt[i * NCB + cid] = c[i];
}

// ---------------- scan stage 1: block-local exclusive scan + block sums ----
__global__ __launch_bounds__(1024) void k_scan1(int* __restrict__ gcnt, int* __restrict__ bsum) {
    __shared__ int sh[1024];
    int t = threadIdx.x;
    int idx = blockIdx.x * 1024 + t;
    int v = (idx < GCNT_TOT) ? gcnt[idx] : 0;
    sh[t] = v;
    __syncthreads();
    for (int off = 1; off < 1024; off <<= 1) {
        int a = sh[t];
        int b = (t >= off) ? sh[t - off] : 0;
        __syncthreads();
        sh[t] = a + b;
        __syncthreads();
    }
    if (idx < GCNT_TOT) gcnt[idx] = sh[t] - v;     // exclusive within block
    if (t == 1023) bsum[blockIdx.x] = sh[1023];
}

// ---------------- scan stage 2: scan the 256 block sums (+ zero bins) ------
__global__ __launch_bounds__(256) void k_scan2(int* __restrict__ bsum, int* __restrict__ bins) {
    __shared__ int sh[256];
    int t = threadIdx.x;
    bins[t] = 0;                                   // zero graph bins (256 ints)
    int v = (t < SCAN_NB) ? bsum[t] : 0;
    sh[t] = v;
    __syncthreads();
    for (int off = 1; off < 256; off <<= 1) {
        int a = sh[t];
        int b = (t >= off) ? sh[t - off] : 0;
        __syncthreads();
        sh[t] = a + b;
        __syncthreads();
    }
    if (t < SCAN_NB) bsum[t] = sh[t] - v;          // exclusive
}

// ---------------- scan stage 3: add block offsets + finalize dinv ----------
__global__ __launch_bounds__(1024) void k_scan3(int* __restrict__ gcnt, const int* __restrict__ bsum,
                                                const int* __restrict__ degg, float* __restrict__ dinv, int N) {
    int idx = blockIdx.x * 1024 + threadIdx.x;
    if (idx < GCNT_TOT) gcnt[idx] += bsum[blockIdx.x];
    if (idx < N) dinv[idx] = rsqrtf(1.0f + (float)degg[idx]);   // +1 = self-loop
}

// ---------------- scatter: LDS-staged local sort by bucket, burst flush ----
__global__ __launch_bounds__(1024) void k_scatter(const int* __restrict__ src, const int* __restrict__ dst,
                                                  const int* __restrict__ gcnt,
                                                  unsigned int* __restrict__ bpk, int E) {
    __shared__ unsigned int stage[CH + 44];  // 50176 B
    __shared__ int hist4[4 * NBUCK];         // 8192 B
    __shared__ int scan[512];                // 2048 B
    __shared__ int excl[NBUCK + 1];
    __shared__ int cur[NBUCK];
    int t = threadIdx.x;
    int cid = chunk_id(blockIdx.x);
    int start = cid * CH;
    int end = min(E, start + CH);
    for (int i = t; i < 4 * NBUCK; i += 1024) hist4[i] = 0;
    __syncthreads();

    // phase 1: load into registers, histogram
    unsigned int w[EPT];
    int kb[EPT];
    int rep = (t & 3) * NBUCK;
    #pragma unroll
    for (int i = 0; i < EPT; i++) {
        int e = start + i * 1024 + t;
        kb[i] = -1;
        if (e < end) {
            int s = __builtin_nontemporal_load(src + e);
            int d = __builtin_nontemporal_load(dst + e);
            unsigned b = bucket_of(d);
            int dl = d - (int)(b * BN);
            kb[i] = (int)b;
            w[i] = ((unsigned)dl << 17) | (unsigned)s;
            atomicAdd(&hist4[rep + (int)b], 1);
        }
    }
    __syncthreads();

    // phase 2: scan 512 bucket counts (512-wide Hillis-Steele)
    int hc = 0;
    if (t < NBUCK) hc = hist4[t] + hist4[NBUCK + t] + hist4[2 * NBUCK + t] + hist4[3 * NBUCK + t];
    if (t < 512) scan[t] = (t < NBUCK) ? hc : 0;
    __syncthreads();
    for (int off = 1; off < 512; off <<= 1) {
        int a = 0;
        if (t < 512 && t >= off) a = scan[t - off];
        __syncthreads();
        if (t < 512 && t >= off) scan[t] += a;
        __syncthreads();
    }
    if (t < NBUCK) {
        int ex = scan[t] - hc;
        excl[t] = ex;
        cur[t] = ex;
    }
    if (t == 0) excl[NBUCK] = end - start;
    __syncthreads();

    // phase 3: rank into bucket-ordered LDS stage
    #pragma unroll
    for (int i = 0; i < EPT; i++) {
        if (kb[i] >= 0) {
            int r = atomicAdd(&cur[kb[i]], 1);
            stage[r] = w[i];
        }
    }
    __syncthreads();

    // phase 4: burst flush, one wave per bucket run (contiguous global writes)
    int wave = t >> 6, lane = t & 63;
    for (int b = wave; b < NBUCK; b += 16) {
        int s0 = excl[b], s1 = excl[b + 1];
        int gbase = gcnt[b * NCB + cid];
        for (int j = s0 + lane; j < s1; j += 64)
            bpk[gbase + (j - s0)] = stage[j];
    }
}

// ---------------- h1b = bf16( dinv * (x @ W1) ) ----------------------------
__global__ __launch_bounds__(256) void k_xw1(const float* __restrict__ x, const float* __restrict__ W1,
                                             const float* __restrict__ dinv,
                                             unsigned short* __restrict__ h1b, int N) {
    __shared__ float sWT[HID * WST];     // transposed + padded: [h][k], stride 132
    __shared__ float sx[16 * 132];
    int t = threadIdx.x;
    for (int i = t; i < HID * NFEAT; i += 256) {
        int h = i >> 7, kk = i & 127;
        sWT[h * WST + kk] = W1[kk * HID + h];
    }
    int local = t >> 4;
    int h     = t & 15;
    int n = blockIdx.x * 16 + local;
    if (n < N) {
        const fvec4* xr = (const fvec4*)(x + (size_t)n * NFEAT);
        fvec4 a = __builtin_nontemporal_load(xr + h * 2);       // dead stream: keep h1b in L2
        fvec4 b = __builtin_nontemporal_load(xr + h * 2 + 1);
        float* sp = sx + local * 132 + h * 8;
        ((fvec4*)sp)[0] = a;
        ((fvec4*)sp)[1] = b;
    }
    __syncthreads();
    if (n >= N) return;
    const fvec4* xr4 = (const fvec4*)(sx + local * 132);
    const fvec4* wr4 = (const fvec4*)(sWT + h * WST);
    float acc = 0.0f;
    #pragma unroll
    for (int k4 = 0; k4 < 32; k4++) {
        fvec4 a = xr4[k4];
        fvec4 b = wr4[k4];
        acc += a.x * b.x + a.y * b.y + a.z * b.z + a.w * b.w;
    }
    h1b[(size_t)n * HID + h] = f2bf(acc * dinv[n]);   // coalesced 2B/lane
}

// ---------------- bg1: u64-packed bucket accumulate + PReLU + W2 -> t2s ----
// 2 lanes/edge (q = feature half). Each lane: 4 ds_add_u64 (feature pairs,
// each field biased +2^23 so both stay non-negative -> carry-free).
__global__ __launch_bounds__(1024) void k_bg1(const unsigned int* __restrict__ bpk, const int* __restrict__ gcnt,
                                              const unsigned short* __restrict__ h1b, const float* __restrict__ dinv,
                                              const int* __restrict__ deg,
                                              const float* __restrict__ b1, const float* __restrict__ prelu_a,
                                              const float* __restrict__ W2,
                                              float* __restrict__ t2s, int E, int N) {
    __shared__ unsigned long long acc[BN * ACST];    // 14112 B
    int t = threadIdx.x;
    int k = blockIdx.x;
    for (int i = t; i < BN * ACST; i += 1024) acc[i] = 0ull;
    __syncthreads();
    int bstart = gcnt[k * NCB];
    int bend = (k < NBUCK - 1) ? gcnt[(k + 1) * NCB] : E;
    int q = t & 1;
    const uint4* h4 = (const uint4*)h1b;            // 16B = 8 bf16 per element

    int e = bstart + (t >> 1);
    unsigned int w = (e < bend) ? __builtin_nontemporal_load(bpk + e) : 0u;
    while (e < bend) {
        int e2 = e + 512;
        unsigned int wn = (e2 < bend) ? __builtin_nontemporal_load(bpk + e2) : 0u;  // prefetch
        int d = (int)(w >> 17);
        int s = (int)(w & 0x1FFFFu);
        uint4 u = h4[(size_t)s * 2 + q];
        unsigned long long* ap = acc + d * ACST + q * 4;
        #pragma unroll
        for (int jj = 0; jj < 4; jj++) {
            unsigned uu = (&u.x)[jj];
            // bf16 -> f32 with exponent +20 (x * 2^20), fused into the unpack
            float flo = __uint_as_float((uu << 16) + 0x0A000000u);
            float fhi = __uint_as_float((uu & 0xFFFF0000u) + 0x0A000000u);
            unsigned lo = (unsigned)(__float2int_rn(flo) + OFF23);
            unsigned hi = (unsigned)(__float2int_rn(fhi) + OFF23);
            atomicAdd(&ap[jj], ((unsigned long long)hi << 32) | (unsigned long long)lo);
        }
        w = wn;
        e = e2;
    }
    __syncthreads();

    // epilogue: t = n*2 + qq; remove bias (deg*2^23), add self, PReLU, @W2
    if (t < BN * 2) {
        int n = t >> 1;
        int qq = t & 1;
        int gn = k * BN + n;
        if (gn < N) {
            float di = dinv[gn];
            int dg = deg[gn];
            long long bias = (long long)dg << 23;
            float a = prelu_a[0];
            const ushortv8* h8 = (const ushortv8*)h1b;
            ushortv8 sv = h8[(size_t)gn * 2 + qq];
            float o0 = 0.0f, o1 = 0.0f;
            #pragma unroll
            for (int jj = 0; jj < 4; jj++) {
                unsigned long long av = acc[n * ACST + qq * 4 + jj];
                float f0 = (float)((long long)(unsigned)av - bias) * S20I;
                float f1 = (float)((long long)(av >> 32) - bias) * S20I;
                int fa = qq * 8 + 2 * jj;
                float tv = di * (f0 + bf2f(sv[2 * jj])) + b1[fa];
                tv = (tv >= 0.0f) ? tv : a * tv;
                o0 += tv * W2[fa * 2 + 0];
                o1 += tv * W2[fa * 2 + 1];
                int fb = fa + 1;
                float tw = di * (f1 + bf2f(sv[2 * jj + 1])) + b1[fb];
                tw = (tw >= 0.0f) ? tw : a * tw;
                o0 += tw * W2[fb * 2 + 0];
                o1 += tw * W2[fb * 2 + 1];
            }
            o0 += __shfl_xor(o0, 1);
            o1 += __shfl_xor(o1, 1);
            if (qq == 0)
                *(float2*)(t2s + (size_t)gn * 2) = make_float2(di * o0, di * o1);
        }
    }
}

// ---------------- bg2: u64-packed accumulate + mean-pool to global bins ----
__global__ __launch_bounds__(1024) void k_bg2(const unsigned int* __restrict__ bpk, const int* __restrict__ gcnt,
                                              const float* __restrict__ t2s, const float* __restrict__ dinv,
                                              const int* __restrict__ deg, const int* __restrict__ batch,
                                              int* __restrict__ bins, int E, int N) {
    __shared__ unsigned long long acc2[BN];
    __shared__ int pg[PSTRIDE];
    int t = threadIdx.x;
    int k = blockIdx.x;
    if (t < BN) acc2[t] = 0ull;
    if (t < PSTRIDE) pg[t] = 0;
    __syncthreads();
    int bstart = gcnt[k * NCB];
    int bend = (k < NBUCK - 1) ? gcnt[(k + 1) * NCB] : E;

    int e = bstart + t;
    unsigned int w = (e < bend) ? __builtin_nontemporal_load(bpk + e) : 0u;
    while (e < bend) {
        int e2 = e + 1024;
        unsigned int wn = (e2 < bend) ? __builtin_nontemporal_load(bpk + e2) : 0u;
        int d = (int)(w >> 17);
        int s = (int)(w & 0x1FFFFu);
        float2 v = *(const float2*)(t2s + (size_t)s * 2);
        unsigned lo = (unsigned)(__float2int_rn(v.x * S18F) + OFF22);
        unsigned hi = (unsigned)(__float2int_rn(v.y * S18F) + OFF22);
        atomicAdd(&acc2[d], ((unsigned long long)hi << 32) | (unsigned long long)lo);
        w = wn;
        e = e2;
    }
    __syncthreads();
    if (t < BN) {
        int gn = k * BN + t;
        if (gn < N) {
            float dd = dinv[gn];
            int dg = deg[gn];
            long long bias = (long long)dg << 22;
            unsigned long long av = acc2[t];
            float2 self = *(const float2*)(t2s + (size_t)gn * 2);
            float v0 = (float)((long long)(unsigned)av - bias) * S18I + self.x;
            float v1 = (float)((long long)(av >> 32) - bias) * S18I + self.y;
            int g = batch[gn];
            atomicAdd(&pg[g * 2 + 0], __float2int_rn(dd * v0 * SPF));
            atomicAdd(&pg[g * 2 + 1], __float2int_rn(dd * v1 * SPF));
            atomicAdd(&pg[128 + g], 1);
        }
    }
    __syncthreads();
    if (t < PSTRIDE && pg[t] != 0) atomicAdd(&bins[t], pg[t]);   // device-scope
}

// ---------------- final: bias + divide from global bins --------------------
__global__ __launch_bounds__(128) void k_final(const int* __restrict__ bins,
                                               const float* __restrict__ b2, float* __restrict__ out) {
    int t = threadIdx.x;
    if (t < NGRAPH * NOUT) {
        int g = t >> 1, c = t & 1;
        float cnt = (float)bins[128 + g];
        float val = (float)bins[t] * SPI;
        out[t] = (val + cnt * b2[c]) / fmaxf(cnt, 1.0f);
    }
}

extern "C" void kernel_launch(void* const* d_in, const int* in_sizes, int n_in,
                              void* d_out, int out_size, void* d_ws, size_t ws_size,
                              hipStream_t stream) {
    const float* x       = (const float*)d_in[0];
    const float* W1      = (const float*)d_in[1];
    const float* b1      = (const float*)d_in[2];
    const float* prelu_a = (const float*)d_in[3];
    const float* W2      = (const float*)d_in[4];
    const float* b2      = (const float*)d_in[5];
    const int*   ei      = (const int*)d_in[6];
    const int*   batch   = (const int*)d_in[7];

    const int N = in_sizes[7];          // 100000
    const int E = in_sizes[6] / 2;      // 6400000
    const int* src = ei;
    const int* dst = ei + E;

    // workspace layout (4-byte words), ~31.5 MB total
    float* ws     = (float*)d_ws;
    float* dinv   = ws;                                        // 100352
    int*   degg   = (int*)(dinv + 100352);                     // 100352
    unsigned short* h1b = (unsigned short*)(degg + 100352);    // 802816 words
    float* t2s    = (float*)((int*)h1b + 802816);              // 200064 (padded)
    int*   gcnt   = (int*)(t2s + 200064);                      // GCNT_TOT (1 MB)
    unsigned int* bpk = (unsigned int*)(gcnt + GCNT_TOT);      // E packed edges
    int*   bins   = (int*)(bpk + E);                           // 256
    int*   bsum   = bins + 256;                                // 256

    float* out = (float*)d_out;

    hipMemsetAsync(degg, 0, (size_t)N * sizeof(int), stream);
    k_count<<<NCB, 1024, 0, stream>>>(dst, gcnt, degg, E);
    k_scan1<<<SCAN_NB, 1024, 0, stream>>>(gcnt, bsum);
    k_scan2<<<1, 256, 0, stream>>>(bsum, bins);
    k_scan3<<<SCAN_NB, 1024, 0, stream>>>(gcnt, bsum, degg, dinv, N);
    k_scatter<<<NCB, 1024, 0, stream>>>(src, dst, gcnt, bpk, E);
    k_xw1<<<(N + 15) / 16, 256, 0, stream>>>(x, W1, dinv, h1b, N);
    k_bg1<<<NBUCK, 1024, 0, stream>>>(bpk, gcnt, h1b, dinv, degg, b1, prelu_a, W2, t2s, E, N);
    k_bg2<<<NBUCK, 1024, 0, stream>>>(bpk, gcnt, t2s, dinv, degg, batch, bins, E, N);
    k_final<<<1, 128, 0, stream>>>(bins, b2, out);
}

// Round 10
// 264.183 us; speedup vs baseline: 1.9528x; 1.9528x over previous
//
#include <hip/hip_runtime.h>

#define NFEAT 128
#define HID 16
#define NOUT 2
#define NGRAPH 64

#define BN 196                     // nodes per bucket
#define NBUCK 512                  // 512 buckets -> 2 blocks/CU on 256 CUs
#define NCB 512                    // scatter chunks (1024-thr blocks, 2/CU)
#define CH 12500                   // chunk length = E/NCB exactly
#define EPT 13                     // edges per thread (13*1024 >= 12500)
#define CAP 13824                  // bucket capacity: mean 12544 + 11.4 sigma
#define PSTRIDE 192                // 128 graph sums + 64 counts
#define WST 132                    // sWT row stride (floats): 128+4 pad
#define ACST 9                     // bg1 u64 acc stride (odd -> bank-pair spread)

// fixed-point scales (int LDS atomics fast; ds_add_f32 ~200cy; global atomics memory-side)
#define S20F 1048576.0f            // 2^20 (bg1 features)
#define S20I 9.5367431640625e-7f   // 2^-20
#define S18F 262144.0f             // 2^18 (bg2 components)
#define S18I 3.814697265625e-6f    // 2^-18
#define SPF  32768.0f              // 2^15 (graph bins)
#define SPI  3.0517578125e-5f      // 2^-15
#define OFF23 0x800000             // per-addend bias, bg1 fields
#define OFF22 0x400000             // per-addend bias, bg2 fields

typedef unsigned short ushortv8 __attribute__((ext_vector_type(8)));
typedef float fvec4 __attribute__((ext_vector_type(4)));

// XCD-aware chunk remap: consecutive chunks stay on one XCD (8 XCDs, rr dispatch)
__device__ __forceinline__ int chunk_id(int bid) { return ((bid & 7) << 6) | (bid >> 3); }

// RNE float -> bf16 bits
__device__ __forceinline__ unsigned short f2bf(float f) {
    unsigned u = __float_as_uint(f);
    return (unsigned short)((u + 0x7FFFu + ((u >> 16) & 1u)) >> 16);
}

__device__ __forceinline__ float bf2f(unsigned short b) {
    return __uint_as_float(((unsigned)b) << 16);
}

__device__ __forceinline__ unsigned bucket_of(int d) { return (unsigned)d / (unsigned)BN; }

// ---------------- scatter: LDS sort by bucket + parallel cursor volley -----
// The 512 per-bucket allocations are issued as ONE volley (8 waves x 64
// independent atomics) BEFORE the block-local scan, hiding their latency.
// Round-6's failure was serial dependent atomics in the flush loop.
__global__ __launch_bounds__(1024) void k_scatter(const int* __restrict__ src, const int* __restrict__ dst,
                                                  int* __restrict__ cursor,
                                                  unsigned int* __restrict__ bpk, int E) {
    __shared__ unsigned int stage[CH + 44];  // 50176 B
    __shared__ int hist4[4 * NBUCK];         // 8192 B (reused: [0..511] = gbase after phase 2)
    __shared__ int scan[512];                // 2048 B
    __shared__ int excl[NBUCK + 1];
    __shared__ int cur[NBUCK];
    int t = threadIdx.x;
    int cid = chunk_id(blockIdx.x);
    int start = cid * CH;
    int end = min(E, start + CH);
    for (int i = t; i < 4 * NBUCK; i += 1024) hist4[i] = 0;
    __syncthreads();

    // phase 1: load into registers, histogram
    unsigned int w[EPT];
    int kb[EPT];
    int rep = (t & 3) * NBUCK;
    #pragma unroll
    for (int i = 0; i < EPT; i++) {
        int e = start + i * 1024 + t;
        kb[i] = -1;
        if (e < end) {
            int s = __builtin_nontemporal_load(src + e);
            int d = __builtin_nontemporal_load(dst + e);
            unsigned b = bucket_of(d);
            int dl = d - (int)(b * BN);
            kb[i] = (int)b;
            w[i] = ((unsigned)dl << 17) | (unsigned)s;
            atomicAdd(&hist4[rep + (int)b], 1);
        }
    }
    __syncthreads();

    // phase 2a: bucket totals + global allocation volley (latency hides under scan)
    int hc = 0, gb = 0;
    if (t < NBUCK) {
        hc = hist4[t] + hist4[NBUCK + t] + hist4[2 * NBUCK + t] + hist4[3 * NBUCK + t];
        if (hc > 0) gb = atomicAdd(&cursor[t], hc);   // independent, pipelined
    }
    // phase 2b: block-local exclusive scan (512-wide Hillis-Steele)
    if (t < 512) scan[t] = (t < NBUCK) ? hc : 0;
    __syncthreads();
    for (int off = 1; off < 512; off <<= 1) {
        int a = 0;
        if (t < 512 && t >= off) a = scan[t - off];
        __syncthreads();
        if (t < 512 && t >= off) scan[t] += a;
        __syncthreads();
    }
    if (t < NBUCK) {
        int ex = scan[t] - hc;
        excl[t] = ex;
        cur[t] = ex;
        hist4[t] = gb;                    // reuse hist4[0..511] as per-bucket global base
    }
    if (t == 0) excl[NBUCK] = end - start;
    __syncthreads();

    // phase 3: rank into bucket-ordered LDS stage
    #pragma unroll
    for (int i = 0; i < EPT; i++) {
        if (kb[i] >= 0) {
            int r = atomicAdd(&cur[kb[i]], 1);
            stage[r] = w[i];
        }
    }
    __syncthreads();

    // phase 4: burst flush, one wave per bucket run (contiguous global writes)
    int wave = t >> 6, lane = t & 63;
    for (int b = wave; b < NBUCK; b += 16) {
        int s0 = excl[b], s1 = excl[b + 1];
        int run = s1 - s0;
        if (run <= 0) continue;
        int gbase = hist4[b];
        int avail = CAP - gbase;
        int lim = min(run, max(avail, 0));   // overflow clamp (statistically unreachable)
        for (int j = lane; j < lim; j += 64)
            bpk[(size_t)b * CAP + gbase + j] = stage[s0 + j];
    }
}

// ---------------- deg: per-bucket dst histogram -> dinv + deg --------------
__global__ __launch_bounds__(1024) void k_deg(const unsigned int* __restrict__ bpk, const int* __restrict__ cursor,
                                              float* __restrict__ dinv, int* __restrict__ deg, int N) {
    __shared__ int h[BN];
    int t = threadIdx.x;
    int k = blockIdx.x;
    if (t < BN) h[t] = 0;
    __syncthreads();
    int bstart = k * CAP;
    int bend = bstart + cursor[k];
    for (int e = bstart + t; e < bend; e += 1024)
        atomicAdd(&h[__builtin_nontemporal_load(bpk + e) >> 17], 1);
    __syncthreads();
    if (t < BN) {
        int gn = k * BN + t;
        if (gn < N) {
            deg[gn] = h[t];
            dinv[gn] = rsqrtf(1.0f + (float)h[t]);   // +1 = self-loop
        }
    }
}

// ---------------- h1b = bf16( dinv * (x @ W1) ) ----------------------------
__global__ __launch_bounds__(256) void k_xw1(const float* __restrict__ x, const float* __restrict__ W1,
                                             const float* __restrict__ dinv,
                                             unsigned short* __restrict__ h1b, int N) {
    __shared__ float sWT[HID * WST];     // transposed + padded: [h][k], stride 132
    __shared__ float sx[16 * 132];
    int t = threadIdx.x;
    for (int i = t; i < HID * NFEAT; i += 256) {
        int h = i >> 7, kk = i & 127;
        sWT[h * WST + kk] = W1[kk * HID + h];
    }
    int local = t >> 4;
    int h     = t & 15;
    int n = blockIdx.x * 16 + local;
    if (n < N) {
        const fvec4* xr = (const fvec4*)(x + (size_t)n * NFEAT);
        fvec4 a = __builtin_nontemporal_load(xr + h * 2);       // dead stream: keep h1b in L2
        fvec4 b = __builtin_nontemporal_load(xr + h * 2 + 1);
        float* sp = sx + local * 132 + h * 8;
        ((fvec4*)sp)[0] = a;
        ((fvec4*)sp)[1] = b;
    }
    __syncthreads();
    if (n >= N) return;
    const fvec4* xr4 = (const fvec4*)(sx + local * 132);
    const fvec4* wr4 = (const fvec4*)(sWT + h * WST);
    float acc = 0.0f;
    #pragma unroll
    for (int k4 = 0; k4 < 32; k4++) {
        fvec4 a = xr4[k4];
        fvec4 b = wr4[k4];
        acc += a.x * b.x + a.y * b.y + a.z * b.z + a.w * b.w;
    }
    h1b[(size_t)n * HID + h] = f2bf(acc * dinv[n]);   // coalesced 2B/lane
}

// ---------------- bg1: u64-packed bucket accumulate + PReLU + W2 -> t2s ----
// 2 lanes/edge (q = feature half). Each lane: 4 ds_add_u64 (feature pairs,
// each field biased +2^23 so both stay non-negative -> carry-free).
__global__ __launch_bounds__(1024) void k_bg1(const unsigned int* __restrict__ bpk, const int* __restrict__ cursor,
                                              const unsigned short* __restrict__ h1b, const float* __restrict__ dinv,
                                              const int* __restrict__ deg,
                                              const float* __restrict__ b1, const float* __restrict__ prelu_a,
                                              const float* __restrict__ W2,
                                              float* __restrict__ t2s, int N) {
    __shared__ unsigned long long acc[BN * ACST];    // 14112 B
    int t = threadIdx.x;
    int k = blockIdx.x;
    for (int i = t; i < BN * ACST; i += 1024) acc[i] = 0ull;
    __syncthreads();
    int bstart = k * CAP;
    int bend = bstart + cursor[k];
    int q = t & 1;
    const uint4* h4 = (const uint4*)h1b;            // 16B = 8 bf16 per element

    int e = bstart + (t >> 1);
    unsigned int w = (e < bend) ? __builtin_nontemporal_load(bpk + e) : 0u;
    while (e < bend) {
        int e2 = e + 512;
        unsigned int wn = (e2 < bend) ? __builtin_nontemporal_load(bpk + e2) : 0u;  // prefetch
        int d = (int)(w >> 17);
        int s = (int)(w & 0x1FFFFu);
        uint4 u = h4[(size_t)s * 2 + q];
        unsigned long long* ap = acc + d * ACST + q * 4;
        #pragma unroll
        for (int jj = 0; jj < 4; jj++) {
            unsigned uu = (&u.x)[jj];
            // bf16 -> f32 with exponent +20 (x * 2^20), fused into the unpack
            float flo = __uint_as_float((uu << 16) + 0x0A000000u);
            float fhi = __uint_as_float((uu & 0xFFFF0000u) + 0x0A000000u);
            unsigned lo = (unsigned)(__float2int_rn(flo) + OFF23);
            unsigned hi = (unsigned)(__float2int_rn(fhi) + OFF23);
            atomicAdd(&ap[jj], ((unsigned long long)hi << 32) | (unsigned long long)lo);
        }
        w = wn;
        e = e2;
    }
    __syncthreads();

    // epilogue: t = n*2 + qq; remove bias (deg*2^23), add self, PReLU, @W2
    if (t < BN * 2) {
        int n = t >> 1;
        int qq = t & 1;
        int gn = k * BN + n;
        if (gn < N) {
            float di = dinv[gn];
            int dg = deg[gn];
            long long bias = (long long)dg << 23;
            float a = prelu_a[0];
            const ushortv8* h8 = (const ushortv8*)h1b;
            ushortv8 sv = h8[(size_t)gn * 2 + qq];
            float o0 = 0.0f, o1 = 0.0f;
            #pragma unroll
            for (int jj = 0; jj < 4; jj++) {
                unsigned long long av = acc[n * ACST + qq * 4 + jj];
                float f0 = (float)((long long)(unsigned)av - bias) * S20I;
                float f1 = (float)((long long)(av >> 32) - bias) * S20I;
                int fa = qq * 8 + 2 * jj;
                float tv = di * (f0 + bf2f(sv[2 * jj])) + b1[fa];
                tv = (tv >= 0.0f) ? tv : a * tv;
                o0 += tv * W2[fa * 2 + 0];
                o1 += tv * W2[fa * 2 + 1];
                int fb = fa + 1;
                float tw = di * (f1 + bf2f(sv[2 * jj + 1])) + b1[fb];
                tw = (tw >= 0.0f) ? tw : a * tw;
                o0 += tw * W2[fb * 2 + 0];
                o1 += tw * W2[fb * 2 + 1];
            }
            o0 += __shfl_xor(o0, 1);
            o1 += __shfl_xor(o1, 1);
            if (qq == 0)
                *(float2*)(t2s + (size_t)gn * 2) = make_float2(di * o0, di * o1);
        }
    }
}

// ---------------- bg2: u64-packed accumulate + mean-pool to global bins ----
__global__ __launch_bounds__(1024) void k_bg2(const unsigned int* __restrict__ bpk, const int* __restrict__ cursor,
                                              const float* __restrict__ t2s, const float* __restrict__ dinv,
                                              const int* __restrict__ deg, const int* __restrict__ batch,
                                              int* __restrict__ bins, int N) {
    __shared__ unsigned long long acc2[BN];
    __shared__ int pg[PSTRIDE];
    int t = threadIdx.x;
    int k = blockIdx.x;
    if (t < BN) acc2[t] = 0ull;
    if (t < PSTRIDE) pg[t] = 0;
    __syncthreads();
    int bstart = k * CAP;
    int bend = bstart + cursor[k];

    int e = bstart + t;
    unsigned int w = (e < bend) ? __builtin_nontemporal_load(bpk + e) : 0u;
    while (e < bend) {
        int e2 = e + 1024;
        unsigned int wn = (e2 < bend) ? __builtin_nontemporal_load(bpk + e2) : 0u;
        int d = (int)(w >> 17);
        int s = (int)(w & 0x1FFFFu);
        float2 v = *(const float2*)(t2s + (size_t)s * 2);
        unsigned lo = (unsigned)(__float2int_rn(v.x * S18F) + OFF22);
        unsigned hi = (unsigned)(__float2int_rn(v.y * S18F) + OFF22);
        atomicAdd(&acc2[d], ((unsigned long long)hi << 32) | (unsigned long long)lo);
        w = wn;
        e = e2;
    }
    __syncthreads();
    if (t < BN) {
        int gn = k * BN + t;
        if (gn < N) {
            float dd = dinv[gn];
            int dg = deg[gn];
            long long bias = (long long)dg << 22;
            unsigned long long av = acc2[t];
            float2 self = *(const float2*)(t2s + (size_t)gn * 2);
            float v0 = (float)((long long)(unsigned)av - bias) * S18I + self.x;
            float v1 = (float)((long long)(av >> 32) - bias) * S18I + self.y;
            int g = batch[gn];
            atomicAdd(&pg[g * 2 + 0], __float2int_rn(dd * v0 * SPF));
            atomicAdd(&pg[g * 2 + 1], __float2int_rn(dd * v1 * SPF));
            atomicAdd(&pg[128 + g], 1);
        }
    }
    __syncthreads();
    if (t < PSTRIDE && pg[t] != 0) atomicAdd(&bins[t], pg[t]);   // device-scope
}

// ---------------- final: bias + divide from global bins --------------------
__global__ __launch_bounds__(128) void k_final(const int* __restrict__ bins,
                                               const float* __restrict__ b2, float* __restrict__ out) {
    int t = threadIdx.x;
    if (t < NGRAPH * NOUT) {
        int g = t >> 1, c = t & 1;
        float cnt = (float)bins[128 + g];
        float val = (float)bins[t] * SPI;
        out[t] = (val + cnt * b2[c]) / fmaxf(cnt, 1.0f);
    }
}

extern "C" void kernel_launch(void* const* d_in, const int* in_sizes, int n_in,
                              void* d_out, int out_size, void* d_ws, size_t ws_size,
                              hipStream_t stream) {
    const float* x       = (const float*)d_in[0];
    const float* W1      = (const float*)d_in[1];
    const float* b1      = (const float*)d_in[2];
    const float* prelu_a = (const float*)d_in[3];
    const float* W2      = (const float*)d_in[4];
    const float* b2      = (const float*)d_in[5];
    const int*   ei      = (const int*)d_in[6];
    const int*   batch   = (const int*)d_in[7];

    const int N = in_sizes[7];          // 100000
    const int E = in_sizes[6] / 2;      // 6400000
    const int* src = ei;
    const int* dst = ei + E;

    // workspace layout (4-byte words), ~33.1 MB total
    float* ws     = (float*)d_ws;
    float* dinv   = ws;                                        // 100352
    int*   deg    = (int*)(dinv + 100352);                     // 100352
    unsigned short* h1b = (unsigned short*)(deg + 100352);     // 802816 words
    float* t2s    = (float*)((int*)h1b + 802816);              // 200064 (padded)
    int*   cursor = (int*)(t2s + 200064);                      // 512
    int*   bins   = cursor + 512;                              // 256 (contiguous w/ cursor)
    unsigned int* bpk = (unsigned int*)(bins + 256);           // 512*13824 = 28.3 MB

    float* out = (float*)d_out;

    hipMemsetAsync(cursor, 0, (512 + 256) * sizeof(int), stream);   // cursor + bins
    k_scatter<<<NCB, 1024, 0, stream>>>(src, dst, cursor, bpk, E);
    k_deg<<<NBUCK, 1024, 0, stream>>>(bpk, cursor, dinv, deg, N);
    k_xw1<<<(N + 15) / 16, 256, 0, stream>>>(x, W1, dinv, h1b, N);
    k_bg1<<<NBUCK, 1024, 0, stream>>>(bpk, cursor, h1b, dinv, deg, b1, prelu_a, W2, t2s, N);
    k_bg2<<<NBUCK, 1024, 0, stream>>>(bpk, cursor, t2s, dinv, deg, batch, bins, N);
    k_final<<<1, 128, 0, stream>>>(bins, b2, out);
}

// Round 11
// 254.610 us; speedup vs baseline: 2.0262x; 1.0376x over previous
//
#include <hip/hip_runtime.h>

#define NFEAT 128
#define HID 16
#define NOUT 2
#define NGRAPH 64

#define BN 196                     // nodes per bucket
#define NBUCK 512                  // 512 buckets -> 2 blocks/CU on 256 CUs
#define NCB 512                    // scatter chunks (1024-thr blocks, 2/CU)
#define CH 12500                   // chunk length = E/NCB exactly
#define EPT 13                     // edges per thread (13*1024 >= 12500)
#define CAP 13824                  // bucket capacity: mean 12544 + 11.4 sigma
#define PSTRIDE 192                // 128 graph sums + 64 counts
#define WST 132                    // sWT row stride (floats): 128+4 pad
#define ACST 9                     // bg1 u64 acc stride (odd -> bank-pair spread)

// fixed-point scales (int LDS atomics fast; ds_add_f32 ~200cy; global atomics memory-side)
#define S20F 1048576.0f            // 2^20 (bg1 features)
#define S20I 9.5367431640625e-7f   // 2^-20
#define S18F 262144.0f             // 2^18 (bg2 components)
#define S18I 3.814697265625e-6f    // 2^-18
#define SPF  32768.0f              // 2^15 (graph bins)
#define SPI  3.0517578125e-5f      // 2^-15
#define OFF23 0x800000             // per-addend bias, bg1 fields
#define OFF22 0x400000             // per-addend bias, bg2 fields

typedef unsigned short ushortv8 __attribute__((ext_vector_type(8)));
typedef float fvec4 __attribute__((ext_vector_type(4)));

// XCD-aware chunk remap: consecutive chunks stay on one XCD (8 XCDs, rr dispatch)
__device__ __forceinline__ int chunk_id(int bid) { return ((bid & 7) << 6) | (bid >> 3); }

// RNE float -> bf16 bits
__device__ __forceinline__ unsigned short f2bf(float f) {
    unsigned u = __float_as_uint(f);
    return (unsigned short)((u + 0x7FFFu + ((u >> 16) & 1u)) >> 16);
}

__device__ __forceinline__ float bf2f(unsigned short b) {
    return __uint_as_float(((unsigned)b) << 16);
}

__device__ __forceinline__ unsigned bucket_of(int d) { return (unsigned)d / (unsigned)BN; }

// ---------------- scatter: LDS sort by bucket + parallel cursor volley -----
__global__ __launch_bounds__(1024) void k_scatter(const int* __restrict__ src, const int* __restrict__ dst,
                                                  int* __restrict__ cursor,
                                                  unsigned int* __restrict__ bpk, int E) {
    __shared__ unsigned int stage[CH + 44];  // 50176 B
    __shared__ int hist4[4 * NBUCK];         // 8192 B (reused: [0..511] = gbase after phase 2)
    __shared__ int scan[512];                // 2048 B
    __shared__ int excl[NBUCK + 1];
    __shared__ int cur[NBUCK];
    int t = threadIdx.x;
    int cid = chunk_id(blockIdx.x);
    int start = cid * CH;
    int end = min(E, start + CH);
    for (int i = t; i < 4 * NBUCK; i += 1024) hist4[i] = 0;
    __syncthreads();

    // phase 1: load into registers, histogram
    unsigned int w[EPT];
    int kb[EPT];
    int rep = (t & 3) * NBUCK;
    #pragma unroll
    for (int i = 0; i < EPT; i++) {
        int e = start + i * 1024 + t;
        kb[i] = -1;
        if (e < end) {
            int s = __builtin_nontemporal_load(src + e);
            int d = __builtin_nontemporal_load(dst + e);
            unsigned b = bucket_of(d);
            int dl = d - (int)(b * BN);
            kb[i] = (int)b;
            w[i] = ((unsigned)dl << 17) | (unsigned)s;
            atomicAdd(&hist4[rep + (int)b], 1);
        }
    }
    __syncthreads();

    // phase 2a: bucket totals + global allocation volley (latency hides under scan)
    int hc = 0, gb = 0;
    if (t < NBUCK) {
        hc = hist4[t] + hist4[NBUCK + t] + hist4[2 * NBUCK + t] + hist4[3 * NBUCK + t];
        if (hc > 0) gb = atomicAdd(&cursor[t], hc);   // independent, pipelined
    }
    // phase 2b: block-local exclusive scan (512-wide Hillis-Steele)
    if (t < 512) scan[t] = (t < NBUCK) ? hc : 0;
    __syncthreads();
    for (int off = 1; off < 512; off <<= 1) {
        int a = 0;
        if (t < 512 && t >= off) a = scan[t - off];
        __syncthreads();
        if (t < 512 && t >= off) scan[t] += a;
        __syncthreads();
    }
    if (t < NBUCK) {
        int ex = scan[t] - hc;
        excl[t] = ex;
        cur[t] = ex;
        hist4[t] = gb;                    // reuse hist4[0..511] as per-bucket global base
    }
    if (t == 0) excl[NBUCK] = end - start;
    __syncthreads();

    // phase 3: rank into bucket-ordered LDS stage
    #pragma unroll
    for (int i = 0; i < EPT; i++) {
        if (kb[i] >= 0) {
            int r = atomicAdd(&cur[kb[i]], 1);
            stage[r] = w[i];
        }
    }
    __syncthreads();

    // phase 4: burst flush, one wave per bucket run (contiguous global writes)
    int wave = t >> 6, lane = t & 63;
    for (int b = wave; b < NBUCK; b += 16) {
        int s0 = excl[b], s1 = excl[b + 1];
        int run = s1 - s0;
        if (run <= 0) continue;
        int gbase = hist4[b];
        int avail = CAP - gbase;
        int lim = min(run, max(avail, 0));   // overflow clamp (statistically unreachable)
        for (int j = lane; j < lim; j += 64)
            bpk[(size_t)b * CAP + gbase + j] = stage[s0 + j];
    }
}

// ---------------- degw1: fused deg histogram + dinv + (x @ W1) -> h1b ------
// phase 1: bucket-k degree histogram from bpk; phase 2: xw1 for the same
// 196 nodes using LDS dinv (4 sub-iterations of the 64-node staged matmul).
__global__ __launch_bounds__(1024) void k_degw1(const unsigned int* __restrict__ bpk, const int* __restrict__ cursor,
                                                const float* __restrict__ x, const float* __restrict__ W1,
                                                int* __restrict__ deg, float* __restrict__ dinv,
                                                unsigned short* __restrict__ h1b, int N) {
    __shared__ int hdeg[BN];             // 784 B
    __shared__ float sdinv[BN];          // 784 B
    __shared__ float sWT[HID * WST];     // 8448 B  transposed W1
    __shared__ float sx[64 * 132];       // 33792 B staged x rows
    int t = threadIdx.x;
    int k = blockIdx.x;
    if (t < BN) hdeg[t] = 0;
    for (int i = t; i < HID * NFEAT; i += 1024) {
        int h = i >> 7, kk = i & 127;
        sWT[h * WST + kk] = W1[kk * HID + h];
    }
    __syncthreads();
    int bstart = k * CAP;
    int bend = bstart + cursor[k];
    for (int e = bstart + t; e < bend; e += 1024)
        atomicAdd(&hdeg[__builtin_nontemporal_load(bpk + e) >> 17], 1);
    __syncthreads();
    if (t < BN) {
        int gn = k * BN + t;
        float di = rsqrtf(1.0f + (float)hdeg[t]);   // +1 = self-loop
        sdinv[t] = di;
        if (gn < N) { deg[gn] = hdeg[t]; dinv[gn] = di; }
    }
    __syncthreads();

    // phase 2: h1b = bf16(dinv * x@W1), 64 nodes per sub-iteration
    int local = t >> 4;                  // 0..63
    int h     = t & 15;
    for (int nb = 0; nb < 4; nb++) {
        int ln = nb * 64 + local;
        int gn = k * BN + ln;
        bool valid = (ln < BN) && (gn < N);
        if (valid) {
            const fvec4* xr = (const fvec4*)(x + (size_t)gn * NFEAT);
            fvec4 a = __builtin_nontemporal_load(xr + h * 2);   // dead stream
            fvec4 b = __builtin_nontemporal_load(xr + h * 2 + 1);
            float* sp = sx + local * 132 + h * 8;
            ((fvec4*)sp)[0] = a;
            ((fvec4*)sp)[1] = b;
        }
        __syncthreads();
        if (valid) {
            const fvec4* xr4 = (const fvec4*)(sx + local * 132);
            const fvec4* wr4 = (const fvec4*)(sWT + h * WST);
            float acc = 0.0f;
            #pragma unroll
            for (int k4 = 0; k4 < 32; k4++) {
                fvec4 a = xr4[k4];
                fvec4 b = wr4[k4];
                acc += a.x * b.x + a.y * b.y + a.z * b.z + a.w * b.w;
            }
            h1b[(size_t)gn * HID + h] = f2bf(acc * sdinv[ln]);
        }
        __syncthreads();
    }
}

// ---------------- bg1: u64-packed 2x-replicated accumulate + epilogue ------
// 2 lanes/edge (q = feature half), unroll-2 (two gathers in flight/lane).
// acc replicated x2 by pair-lane parity to halve LDS atomic collisions.
__global__ __launch_bounds__(1024, 8) void k_bg1(const unsigned int* __restrict__ bpk, const int* __restrict__ cursor,
                                                 const unsigned short* __restrict__ h1b, const float* __restrict__ dinv,
                                                 const int* __restrict__ deg,
                                                 const float* __restrict__ b1, const float* __restrict__ prelu_a,
                                                 const float* __restrict__ W2,
                                                 float* __restrict__ t2s, int N) {
    __shared__ unsigned long long acc[2][BN * ACST];    // 28224 B
    int t = threadIdx.x;
    int k = blockIdx.x;
    for (int i = t; i < 2 * BN * ACST; i += 1024) ((unsigned long long*)acc)[i] = 0ull;
    __syncthreads();
    int bstart = k * CAP;
    int bend = bstart + cursor[k];
    int q = t & 1;
    int cp = (t >> 1) & 1;                          // replication copy
    unsigned long long* myacc = acc[cp];
    const uint4* h4 = (const uint4*)h1b;            // 16B = 8 bf16 per element

    int e = bstart + (t >> 1);
    unsigned int w0 = (e < bend) ? __builtin_nontemporal_load(bpk + e) : 0u;
    unsigned int w1 = (e + 512 < bend) ? __builtin_nontemporal_load(bpk + e + 512) : 0u;
    while (e < bend) {
        int eN = e + 1024;
        unsigned int w0n = (eN < bend) ? __builtin_nontemporal_load(bpk + eN) : 0u;
        unsigned int w1n = (eN + 512 < bend) ? __builtin_nontemporal_load(bpk + eN + 512) : 0u;
        bool hasB = (e + 512 < bend);
        int dA = (int)(w0 >> 17), sA = (int)(w0 & 0x1FFFFu);
        int dB = (int)(w1 >> 17), sB = (int)(w1 & 0x1FFFFu);
        uint4 uA = h4[(size_t)sA * 2 + q];          // two independent gathers in flight
        uint4 uB;
        if (hasB) uB = h4[(size_t)sB * 2 + q];
        unsigned long long* apA = myacc + dA * ACST + q * 4;
        #pragma unroll
        for (int jj = 0; jj < 4; jj++) {
            unsigned uu = (&uA.x)[jj];
            float flo = __uint_as_float((uu << 16) + 0x0A000000u);          // bf16 * 2^20
            float fhi = __uint_as_float((uu & 0xFFFF0000u) + 0x0A000000u);
            unsigned lo = (unsigned)(__float2int_rn(flo) + OFF23);
            unsigned hi = (unsigned)(__float2int_rn(fhi) + OFF23);
            atomicAdd(&apA[jj], ((unsigned long long)hi << 32) | (unsigned long long)lo);
        }
        if (hasB) {
            unsigned long long* apB = myacc + dB * ACST + q * 4;
            #pragma unroll
            for (int jj = 0; jj < 4; jj++) {
                unsigned uu = (&uB.x)[jj];
                float flo = __uint_as_float((uu << 16) + 0x0A000000u);
                float fhi = __uint_as_float((uu & 0xFFFF0000u) + 0x0A000000u);
                unsigned lo = (unsigned)(__float2int_rn(flo) + OFF23);
                unsigned hi = (unsigned)(__float2int_rn(fhi) + OFF23);
                atomicAdd(&apB[jj], ((unsigned long long)hi << 32) | (unsigned long long)lo);
            }
        }
        w0 = w0n; w1 = w1n; e = eN;
    }
    __syncthreads();

    // epilogue: sum replicas field-wise in 64-bit (lo sums can reach 2^32),
    // remove bias (deg*2^23 total across copies), add self, PReLU, @W2
    if (t < BN * 2) {
        int n = t >> 1;
        int qq = t & 1;
        int gn = k * BN + n;
        if (gn < N) {
            float di = dinv[gn];
            int dg = deg[gn];
            long long bias = (long long)dg << 23;
            float a = prelu_a[0];
            const ushortv8* h8 = (const ushortv8*)h1b;
            ushortv8 sv = h8[(size_t)gn * 2 + qq];
            float o0 = 0.0f, o1 = 0.0f;
            #pragma unroll
            for (int jj = 0; jj < 4; jj++) {
                unsigned long long a0 = acc[0][n * ACST + qq * 4 + jj];
                unsigned long long a1 = acc[1][n * ACST + qq * 4 + jj];
                long long losum = (long long)(unsigned)a0 + (long long)(unsigned)a1;
                long long hisum = (long long)(a0 >> 32) + (long long)(a1 >> 32);
                float f0 = (float)(losum - bias) * S20I;
                float f1 = (float)(hisum - bias) * S20I;
                int fa = qq * 8 + 2 * jj;
                float tv = di * (f0 + bf2f(sv[2 * jj])) + b1[fa];
                tv = (tv >= 0.0f) ? tv : a * tv;
                o0 += tv * W2[fa * 2 + 0];
                o1 += tv * W2[fa * 2 + 1];
                int fb = fa + 1;
                float tw = di * (f1 + bf2f(sv[2 * jj + 1])) + b1[fb];
                tw = (tw >= 0.0f) ? tw : a * tw;
                o0 += tw * W2[fb * 2 + 0];
                o1 += tw * W2[fb * 2 + 1];
            }
            o0 += __shfl_xor(o0, 1);
            o1 += __shfl_xor(o1, 1);
            if (qq == 0)
                *(float2*)(t2s + (size_t)gn * 2) = make_float2(di * o0, di * o1);
        }
    }
}

// ---------------- bg2: u64-packed 2x-replicated accumulate + mean-pool -----
__global__ __launch_bounds__(1024, 8) void k_bg2(const unsigned int* __restrict__ bpk, const int* __restrict__ cursor,
                                                 const float* __restrict__ t2s, const float* __restrict__ dinv,
                                                 const int* __restrict__ deg, const int* __restrict__ batch,
                                                 int* __restrict__ bins, int N) {
    __shared__ unsigned long long acc2[2][BN];   // 3136 B
    __shared__ int pg[PSTRIDE];
    int t = threadIdx.x;
    int k = blockIdx.x;
    for (int i = t; i < 2 * BN; i += 1024) ((unsigned long long*)acc2)[i] = 0ull;
    if (t < PSTRIDE) pg[t] = 0;
    __syncthreads();
    int bstart = k * CAP;
    int bend = bstart + cursor[k];
    int cp = t & 1;
    unsigned long long* myacc = acc2[cp];

    int e = bstart + t;
    unsigned int w0 = (e < bend) ? __builtin_nontemporal_load(bpk + e) : 0u;
    unsigned int w1 = (e + 1024 < bend) ? __builtin_nontemporal_load(bpk + e + 1024) : 0u;
    while (e < bend) {
        int eN = e + 2048;
        unsigned int w0n = (eN < bend) ? __builtin_nontemporal_load(bpk + eN) : 0u;
        unsigned int w1n = (eN + 1024 < bend) ? __builtin_nontemporal_load(bpk + eN + 1024) : 0u;
        bool hasB = (e + 1024 < bend);
        int dA = (int)(w0 >> 17), sA = (int)(w0 & 0x1FFFFu);
        int dB = (int)(w1 >> 17), sB = (int)(w1 & 0x1FFFFu);
        float2 vA = *(const float2*)(t2s + (size_t)sA * 2);
        float2 vB;
        if (hasB) vB = *(const float2*)(t2s + (size_t)sB * 2);
        {
            unsigned lo = (unsigned)(__float2int_rn(vA.x * S18F) + OFF22);
            unsigned hi = (unsigned)(__float2int_rn(vA.y * S18F) + OFF22);
            atomicAdd(&myacc[dA], ((unsigned long long)hi << 32) | (unsigned long long)lo);
        }
        if (hasB) {
            unsigned lo = (unsigned)(__float2int_rn(vB.x * S18F) + OFF22);
            unsigned hi = (unsigned)(__float2int_rn(vB.y * S18F) + OFF22);
            atomicAdd(&myacc[dB], ((unsigned long long)hi << 32) | (unsigned long long)lo);
        }
        w0 = w0n; w1 = w1n; e = eN;
    }
    __syncthreads();
    if (t < BN) {
        int gn = k * BN + t;
        if (gn < N) {
            float dd = dinv[gn];
            int dg = deg[gn];
            long long bias = (long long)dg << 22;
            unsigned long long a0 = acc2[0][t];
            unsigned long long a1 = acc2[1][t];
            long long losum = (long long)(unsigned)a0 + (long long)(unsigned)a1;
            long long hisum = (long long)(a0 >> 32) + (long long)(a1 >> 32);
            float2 self = *(const float2*)(t2s + (size_t)gn * 2);
            float v0 = (float)(losum - bias) * S18I + self.x;
            float v1 = (float)(hisum - bias) * S18I + self.y;
            int g = batch[gn];
            atomicAdd(&pg[g * 2 + 0], __float2int_rn(dd * v0 * SPF));
            atomicAdd(&pg[g * 2 + 1], __float2int_rn(dd * v1 * SPF));
            atomicAdd(&pg[128 + g], 1);
        }
    }
    __syncthreads();
    if (t < PSTRIDE && pg[t] != 0) atomicAdd(&bins[t], pg[t]);   // device-scope
}

// ---------------- final: bias + divide from global bins --------------------
__global__ __launch_bounds__(128) void k_final(const int* __restrict__ bins,
                                               const float* __restrict__ b2, float* __restrict__ out) {
    int t = threadIdx.x;
    if (t < NGRAPH * NOUT) {
        int g = t >> 1, c = t & 1;
        float cnt = (float)bins[128 + g];
        float val = (float)bins[t] * SPI;
        out[t] = (val + cnt * b2[c]) / fmaxf(cnt, 1.0f);
    }
}

extern "C" void kernel_launch(void* const* d_in, const int* in_sizes, int n_in,
                              void* d_out, int out_size, void* d_ws, size_t ws_size,
                              hipStream_t stream) {
    const float* x       = (const float*)d_in[0];
    const float* W1      = (const float*)d_in[1];
    const float* b1      = (const float*)d_in[2];
    const float* prelu_a = (const float*)d_in[3];
    const float* W2      = (const float*)d_in[4];
    const float* b2      = (const float*)d_in[5];
    const int*   ei      = (const int*)d_in[6];
    const int*   batch   = (const int*)d_in[7];

    const int N = in_sizes[7];          // 100000
    const int E = in_sizes[6] / 2;      // 6400000
    const int* src = ei;
    const int* dst = ei + E;

    // workspace layout (4-byte words), ~33.1 MB total
    float* ws     = (float*)d_ws;
    float* dinv   = ws;                                        // 100352
    int*   deg    = (int*)(dinv + 100352);                     // 100352
    unsigned short* h1b = (unsigned short*)(deg + 100352);     // 802816 words
    float* t2s    = (float*)((int*)h1b + 802816);              // 200064 (padded)
    int*   cursor = (int*)(t2s + 200064);                      // 512
    int*   bins   = cursor + 512;                              // 256 (contiguous w/ cursor)
    unsigned int* bpk = (unsigned int*)(bins + 256);           // 512*13824 = 28.3 MB

    float* out = (float*)d_out;

    hipMemsetAsync(cursor, 0, (512 + 256) * sizeof(int), stream);   // cursor + bins
    k_scatter<<<NCB, 1024, 0, stream>>>(src, dst, cursor, bpk, E);
    k_degw1<<<NBUCK, 1024, 0, stream>>>(bpk, cursor, x, W1, deg, dinv, h1b, N);
    k_bg1<<<NBUCK, 1024, 0, stream>>>(bpk, cursor, h1b, dinv, deg, b1, prelu_a, W2, t2s, N);
    k_bg2<<<NBUCK, 1024, 0, stream>>>(bpk, cursor, t2s, dinv, deg, batch, bins, N);
    k_final<<<1, 128, 0, stream>>>(bins, b2, out);
}